// Round 2
// baseline (60505.054 us; speedup 1.0000x reference)
//
#include <hip/hip_runtime.h>
#include <cstddef>

#define B_SZ 32
#define T_LEN 1000
#define D_SZ 512
#define H_SZ 512
#define TWO_H 1024
#define LN_EPS 1e-5f

// ---------------------------------------------------------------------------
// Transpose the two grouped-weight tensors [G=8][64][64] from [g][i][o] to
// [g][o][i] so the per-output dot products can use contiguous float4 loads.
// ---------------------------------------------------------------------------
__global__ __launch_bounds__(256) void k_tr(const float* __restrict__ w_in,
                                            const float* __restrict__ w_out,
                                            float* __restrict__ t_in,
                                            float* __restrict__ t_out) {
    int idx = blockIdx.x * 256 + threadIdx.x;   // 65536 threads total
    int sel = idx >> 15;                        // 0: w_in, 1: w_out
    int r   = idx & 32767;                      // 0..32767
    int g = r >> 12, rem = r & 4095, i = rem >> 6, o = rem & 63;
    const float* src = sel ? w_out : w_in;
    float*       dst = sel ? t_out : t_in;
    dst[(g << 12) + (o << 6) + i] = src[(g << 12) + (i << 6) + o];
}

// ---------------------------------------------------------------------------
// Fused: h_in = grouped_linear(x, w_in); w = h_in @ Wrec^T; w = LayerNorm(w)
// One block = 16 rows (a row is one (b,t)). 256 threads.
// Each thread owns 4 consecutive output columns (j0 = tid*4) for all 16 rows.
// ---------------------------------------------------------------------------
__global__ __launch_bounds__(256) void k_pre(const float* __restrict__ x,
                                             const float* __restrict__ t_in,   // [g][o][i]
                                             const float* __restrict__ w_rec,  // [1024][512]
                                             const float* __restrict__ gamma,
                                             const float* __restrict__ beta,
                                             float* __restrict__ w_pre) {
    __shared__ alignas(16) float xt[16][512];
    __shared__ alignas(16) float hin[16][512];
    __shared__ float redS[16][4];
    __shared__ float redQ[16][4];

    const int tid  = threadIdx.x;
    const int row0 = blockIdx.x * 16;

    // ---- load 16 x-rows into LDS (float4, coalesced) ----
    for (int i = tid; i < 16 * 128; i += 256) {
        int rr = i >> 7, c4 = i & 127;
        ((float4*)xt[rr])[c4] =
            ((const float4*)(x + (size_t)(row0 + rr) * 512))[c4];
    }
    __syncthreads();

    // ---- grouped input projection: hin[rr][h] ----
    for (int i = tid; i < 16 * 512; i += 256) {
        int rr = i >> 9, hh = i & 511;
        int g = hh >> 6, o = hh & 63;
        const float4* wc = (const float4*)(t_in + (g << 12) + (o << 6));
        const float4* xr = (const float4*)(xt[rr] + (g << 6));
        float acc = 0.f;
#pragma unroll
        for (int ii = 0; ii < 16; ++ii) {
            float4 a = xr[ii], w = wc[ii];
            acc += a.x * w.x + a.y * w.y + a.z * w.z + a.w * w.w;
        }
        hin[rr][hh] = acc;
    }
    __syncthreads();

    // ---- dense GEMM: acc[rr][jj] = hin[rr][:] . w_rec[j0+jj][:] ----
    const int j0 = tid * 4;
    float acc[16][4];
#pragma unroll
    for (int rr = 0; rr < 16; ++rr)
#pragma unroll
        for (int jj = 0; jj < 4; ++jj) acc[rr][jj] = 0.f;

    for (int k = 0; k < 512; k += 4) {
        float4 wv0 = *(const float4*)(w_rec + (size_t)(j0 + 0) * 512 + k);
        float4 wv1 = *(const float4*)(w_rec + (size_t)(j0 + 1) * 512 + k);
        float4 wv2 = *(const float4*)(w_rec + (size_t)(j0 + 2) * 512 + k);
        float4 wv3 = *(const float4*)(w_rec + (size_t)(j0 + 3) * 512 + k);
#pragma unroll
        for (int rr = 0; rr < 16; ++rr) {
            float4 hv = *(const float4*)(&hin[rr][k]);
            acc[rr][0] += hv.x * wv0.x + hv.y * wv0.y + hv.z * wv0.z + hv.w * wv0.w;
            acc[rr][1] += hv.x * wv1.x + hv.y * wv1.y + hv.z * wv1.z + hv.w * wv1.w;
            acc[rr][2] += hv.x * wv2.x + hv.y * wv2.y + hv.z * wv2.z + hv.w * wv2.w;
            acc[rr][3] += hv.x * wv3.x + hv.y * wv3.y + hv.z * wv3.z + hv.w * wv3.w;
        }
    }

    // ---- LayerNorm over j (1024) per row ----
    const int lane = tid & 63, wv = tid >> 6;
#pragma unroll
    for (int rr = 0; rr < 16; ++rr) {
        float s = acc[rr][0] + acc[rr][1] + acc[rr][2] + acc[rr][3];
        float q = acc[rr][0] * acc[rr][0] + acc[rr][1] * acc[rr][1] +
                  acc[rr][2] * acc[rr][2] + acc[rr][3] * acc[rr][3];
#pragma unroll
        for (int off = 1; off < 64; off <<= 1) {
            s += __shfl_xor(s, off);
            q += __shfl_xor(q, off);
        }
        if (lane == 0) { redS[rr][wv] = s; redQ[rr][wv] = q; }
    }
    __syncthreads();

    float4 gv = *(const float4*)(gamma + j0);
    float4 bv = *(const float4*)(beta + j0);
#pragma unroll
    for (int rr = 0; rr < 16; ++rr) {
        float s = redS[rr][0] + redS[rr][1] + redS[rr][2] + redS[rr][3];
        float q = redQ[rr][0] + redQ[rr][1] + redQ[rr][2] + redQ[rr][3];
        float mu  = s * (1.f / 1024.f);
        float var = q * (1.f / 1024.f) - mu * mu;
        float inv = rsqrtf(var + LN_EPS);
        float4 o;
        o.x = (acc[rr][0] - mu) * inv * gv.x + bv.x;
        o.y = (acc[rr][1] - mu) * inv * gv.y + bv.y;
        o.z = (acc[rr][2] - mu) * inv * gv.z + bv.z;
        o.w = (acc[rr][3] - mu) * inv * gv.w + bv.w;
        *(float4*)(w_pre + ((size_t)(row0 + rr) << 10) + j0) = o;
    }
}

// ---------------------------------------------------------------------------
// LiGRU scan. One block per batch b (32 blocks x 1024 threads). h in LDS.
// Thread j computes gate j: gates[j] = w_pre[b,t,j] + h . u_rec[j,:]
// Writes h_t into hs (= d_out, transformed in-place later).
// ---------------------------------------------------------------------------
__global__ __launch_bounds__(1024) void k_scan(const float* __restrict__ w_pre,
                                               const float* __restrict__ u,  // [1024][512]
                                               float* __restrict__ hs) {
    __shared__ alignas(16) float h[512];
    __shared__ alignas(16) float gl[1024];
    const int j = threadIdx.x;
    const int b = blockIdx.x;
    if (j < 512) h[j] = 0.f;
    __syncthreads();

    const float* urow = u + (size_t)j * 512;
    const float* wrow = w_pre + ((size_t)b * T_LEN) * 1024 + j;
    float* hrow = hs + ((size_t)b * T_LEN) * 512 + j;

    for (int t = 0; t < T_LEN; ++t) {
        float accv = wrow[(size_t)t * 1024];
#pragma unroll 8
        for (int k = 0; k < 512; k += 4) {
            float4 uv = *(const float4*)(urow + k);
            float4 hv = *(const float4*)(&h[k]);
            accv += uv.x * hv.x + uv.y * hv.y + uv.z * hv.z + uv.w * hv.w;
        }
        gl[j] = accv;
        __syncthreads();
        if (j < 512) {
            float a  = accv;                         // gate a_j
            float zl = gl[512 + j];
            float z  = 1.f / (1.f + __expf(-zl));    // sigmoid
            float hc = fmaxf(a, 0.f);                // relu
            float hn = z * h[j] + (1.f - z) * hc;
            h[j] = hn;
            hrow[(size_t)t * 512] = hn;
        }
        __syncthreads();
    }
}

// ---------------------------------------------------------------------------
// Output grouped linear, in-place on d_out (which holds hs after k_scan).
// One block = 8 rows, 256 threads.
// ---------------------------------------------------------------------------
__global__ __launch_bounds__(256) void k_out(const float* __restrict__ t_out, // [g][o][i]
                                             float* __restrict__ io) {
    __shared__ alignas(16) float ht[8][512];
    const int tid  = threadIdx.x;
    const int row0 = blockIdx.x * 8;

    for (int i = tid; i < 8 * 128; i += 256) {
        int rr = i >> 7, c4 = i & 127;
        ((float4*)ht[rr])[c4] =
            ((const float4*)(io + (size_t)(row0 + rr) * 512))[c4];
    }
    __syncthreads();

    for (int i = tid; i < 8 * 512; i += 256) {
        int rr = i >> 9, dd = i & 511;
        int g = dd >> 6, o = dd & 63;
        const float4* wc = (const float4*)(t_out + (g << 12) + (o << 6));
        const float4* hr = (const float4*)(ht[rr] + (g << 6));
        float acc = 0.f;
#pragma unroll
        for (int ii = 0; ii < 16; ++ii) {
            float4 a = hr[ii], w = wc[ii];
            acc += a.x * w.x + a.y * w.y + a.z * w.z + a.w * w.w;
        }
        io[(size_t)(row0 + rr) * 512 + dd] = acc;
    }
}

// ---------------------------------------------------------------------------
extern "C" void kernel_launch(void* const* d_in, const int* in_sizes, int n_in,
                              void* d_out, int out_size, void* d_ws, size_t ws_size,
                              hipStream_t stream) {
    const float* x      = (const float*)d_in[0];
    const float* w_in   = (const float*)d_in[1];
    const float* w_rec  = (const float*)d_in[2];
    const float* u_rec  = (const float*)d_in[3];
    const float* gamma  = (const float*)d_in[4];
    const float* beta   = (const float*)d_in[5];
    const float* w_out  = (const float*)d_in[6];
    float* out = (float*)d_out;

    // workspace layout
    float* w_pre = (float*)d_ws;                         // 32000*1024 f32 = 131072000 B
    float* t_in  = w_pre + (size_t)B_SZ * T_LEN * 1024;  // 32768 f32
    float* t_out = t_in + 32768;                         // 32768 f32

    hipLaunchKernelGGL(k_tr, dim3(256), dim3(256), 0, stream, w_in, w_out, t_in, t_out);
    hipLaunchKernelGGL(k_pre, dim3(2000), dim3(256), 0, stream,
                       x, t_in, w_rec, gamma, beta, w_pre);
    hipLaunchKernelGGL(k_scan, dim3(B_SZ), dim3(1024), 0, stream, w_pre, u_rec, out);
    hipLaunchKernelGGL(k_out, dim3(4000), dim3(256), 0, stream, t_out, out);
}

// Round 4
// 15377.213 us; speedup vs baseline: 3.9347x; 3.9347x over previous
//
#include <hip/hip_runtime.h>
#include <cstddef>

#define B_SZ 32
#define T_LEN 1000
#define LN_EPS 1e-5f

// ---------------------------------------------------------------------------
// Fused: h_in = grouped_linear(x, w_in); w = h_in @ Wrec^T; w = LayerNorm(w)
// One block = 16 rows. 256 threads. w_in used untransposed: column hoisted to
// registers (coalesced across lanes), x broadcast from LDS.
// ---------------------------------------------------------------------------
__global__ __launch_bounds__(256) void k_pre(const float* __restrict__ x,
                                             const float* __restrict__ w_in,   // [g][i][o]
                                             const float* __restrict__ w_rec,  // [1024][512]
                                             const float* __restrict__ gamma,
                                             const float* __restrict__ beta,
                                             float* __restrict__ w_pre) {
    __shared__ alignas(16) float xt[16][512];
    __shared__ alignas(16) float hin[16][512];
    __shared__ float redS[16][4];
    __shared__ float redQ[16][4];

    const int tid  = threadIdx.x;
    const int row0 = blockIdx.x * 16;

    // ---- load 16 x-rows into LDS (float4, coalesced) ----
    for (int i = tid; i < 16 * 128; i += 256) {
        int rr = i >> 7, c4 = i & 127;
        ((float4*)xt[rr])[c4] =
            ((const float4*)(x + (size_t)(row0 + rr) * 512))[c4];
    }
    __syncthreads();

    // ---- grouped input projection: hin[rr][c] ----
    for (int q = 0; q < 2; ++q) {
        const int c = tid + (q << 8);
        const int g = c >> 6, o = c & 63;
        const float* wb = w_in + (g << 12) + o;   // stride 64 over i, coalesced over lanes
        float wcol[64];
#pragma unroll
        for (int ii = 0; ii < 64; ++ii) wcol[ii] = wb[ii << 6];
#pragma unroll 4
        for (int rr = 0; rr < 16; ++rr) {
            float acc = 0.f;
#pragma unroll
            for (int ii = 0; ii < 64; ++ii) acc += xt[rr][(g << 6) + ii] * wcol[ii];
            hin[rr][c] = acc;
        }
    }
    __syncthreads();

    // ---- dense GEMM: acc[rr][jj] = hin[rr][:] . w_rec[j0+jj][:] ----
    const int j0 = tid * 4;
    float acc[16][4];
#pragma unroll
    for (int rr = 0; rr < 16; ++rr)
#pragma unroll
        for (int jj = 0; jj < 4; ++jj) acc[rr][jj] = 0.f;

    for (int k = 0; k < 512; k += 4) {
        float4 wv0 = *(const float4*)(w_rec + (size_t)(j0 + 0) * 512 + k);
        float4 wv1 = *(const float4*)(w_rec + (size_t)(j0 + 1) * 512 + k);
        float4 wv2 = *(const float4*)(w_rec + (size_t)(j0 + 2) * 512 + k);
        float4 wv3 = *(const float4*)(w_rec + (size_t)(j0 + 3) * 512 + k);
#pragma unroll
        for (int rr = 0; rr < 16; ++rr) {
            float4 hv = *(const float4*)(&hin[rr][k]);
            acc[rr][0] += hv.x * wv0.x + hv.y * wv0.y + hv.z * wv0.z + hv.w * wv0.w;
            acc[rr][1] += hv.x * wv1.x + hv.y * wv1.y + hv.z * wv1.z + hv.w * wv1.w;
            acc[rr][2] += hv.x * wv2.x + hv.y * wv2.y + hv.z * wv2.z + hv.w * wv2.w;
            acc[rr][3] += hv.x * wv3.x + hv.y * wv3.y + hv.z * wv3.z + hv.w * wv3.w;
        }
    }

    // ---- LayerNorm over j (1024) per row ----
    const int lane = tid & 63, wv = tid >> 6;
#pragma unroll
    for (int rr = 0; rr < 16; ++rr) {
        float s = acc[rr][0] + acc[rr][1] + acc[rr][2] + acc[rr][3];
        float q = acc[rr][0] * acc[rr][0] + acc[rr][1] * acc[rr][1] +
                  acc[rr][2] * acc[rr][2] + acc[rr][3] * acc[rr][3];
#pragma unroll
        for (int off = 1; off < 64; off <<= 1) {
            s += __shfl_xor(s, off);
            q += __shfl_xor(q, off);
        }
        if (lane == 0) { redS[rr][wv] = s; redQ[rr][wv] = q; }
    }
    __syncthreads();

    float4 gv = *(const float4*)(gamma + j0);
    float4 bv = *(const float4*)(beta + j0);
#pragma unroll
    for (int rr = 0; rr < 16; ++rr) {
        float s = redS[rr][0] + redS[rr][1] + redS[rr][2] + redS[rr][3];
        float q = redQ[rr][0] + redQ[rr][1] + redQ[rr][2] + redQ[rr][3];
        float mu  = s * (1.f / 1024.f);
        float var = q * (1.f / 1024.f) - mu * mu;
        float inv = rsqrtf(var + LN_EPS);
        float4 o;
        o.x = (acc[rr][0] - mu) * inv * gv.x + bv.x;
        o.y = (acc[rr][1] - mu) * inv * gv.y + bv.y;
        o.z = (acc[rr][2] - mu) * inv * gv.z + bv.z;
        o.w = (acc[rr][3] - mu) * inv * gv.w + bv.w;
        *(float4*)(w_pre + ((size_t)(row0 + rr) << 10) + j0) = o;
    }
}

// ---------------------------------------------------------------------------
// LiGRU scan, 8 blocks per batch (256 blocks, all co-resident). Pure fp32.
// Block (s = bid>>5, b = bid&31) owns h-indices [s*64, s*64+64):
//   u rows J (a-gates) and 512+J (z-gates) in REGISTERS (f32, 64 VGPR).
// Per step: stage batch's h (f32, agent atomics) -> swizzled f32 LDS;
// 16x float4-dot/thread; shfl-reduce over kk; 64 threads update h (f32 regs);
// ping-pong h buffer + fenced monotonic 8-block spin barrier.
// ---------------------------------------------------------------------------
__global__ __launch_bounds__(1024) void k_scan(const float* __restrict__ w_pre,
                                               const float* __restrict__ u,   // [1024][512]
                                               float* __restrict__ hs,        // [B][T][512]
                                               float* hbuf,                   // [2][32][512]
                                               int* cnt) {                    // [32][32]
    __shared__ alignas(16) float hsh[512];
    __shared__ float gsum[128];

    const int tid = threadIdx.x;
    const int b   = blockIdx.x & 31;
    const int s   = blockIdx.x >> 5;
    const int J0  = s << 6;
    const int row = tid >> 3;
    const int kk  = tid & 7;
    const int jj  = (row < 64) ? (J0 + row) : (448 + J0 + row);  // z-rows: 512+J0+(row-64)

    // ---- load this thread's u slice into registers (one-time, f32) ----
    float ur[64];
    {
        const float4* up = (const float4*)(u + (size_t)jj * 512 + (kk << 6));
#pragma unroll
        for (int m = 0; m < 16; ++m) {
            float4 v = up[m];
            ur[4 * m + 0] = v.x; ur[4 * m + 1] = v.y;
            ur[4 * m + 2] = v.z; ur[4 * m + 3] = v.w;
        }
    }

    const float* wbase = w_pre + ((size_t)b * T_LEN) * 1024 + jj;
    float* outbase = hs + ((size_t)b * T_LEN) * 512 + J0;
    int* mycnt = cnt + (b << 5);
    const char* hb8 = (const char*)hsh;

    float hreg = 0.f;   // own h value (tid < 64), carried in f32 across steps

    for (int t = 0; t < T_LEN; ++t) {
        float* hb_in  = hbuf + ((t & 1) << 14) + (b << 9);
        float* hb_out = hbuf + (((t + 1) & 1) << 14) + (b << 9);

        // ---- stage h -> swizzled f32 LDS ----
        // h-chunk c (4 floats) stored at LDS chunk a = (c&~7) | ((c^(c>>4))&7)
        if (tid < 512) {
            float hv = __hip_atomic_load(hb_in + tid, __ATOMIC_RELAXED,
                                         __HIP_MEMORY_SCOPE_AGENT);
            int c = tid >> 2, r = tid & 3;
            int a = (c & ~7) | ((c ^ (c >> 4)) & 7);
            hsh[(a << 2) | r] = hv;
        }
        __syncthreads();

        // ---- dot: 64 f32 MACs via 16 float4 LDS reads (conflict-free) ----
        float acc = 0.f;
        const int base = kk << 8;   // byte base of this thread's 256B h-span
#pragma unroll
        for (int i = 0; i < 16; ++i) {
            int off = base + (((i & 8) | ((i ^ kk) & 7)) << 4);
            float4 hv = *(const float4*)(hb8 + off);
            acc += ur[4 * i + 0] * hv.x + ur[4 * i + 1] * hv.y +
                   ur[4 * i + 2] * hv.z + ur[4 * i + 3] * hv.w;
        }
        acc += __shfl_xor(acc, 1);
        acc += __shfl_xor(acc, 2);
        acc += __shfl_xor(acc, 4);
        if (kk == 0) gsum[row] = acc + wbase[(size_t)t << 10];
        __syncthreads();

        // ---- h update (64 threads) ----
        if (tid < 64) {
            float a  = gsum[tid];
            float zl = gsum[64 + tid];
            float z  = 1.f / (1.f + __expf(-zl));
            float hn = z * hreg + (1.f - z) * fmaxf(a, 0.f);
            hreg = hn;
            __hip_atomic_store(hb_out + J0 + tid, hn, __ATOMIC_RELAXED,
                               __HIP_MEMORY_SCOPE_AGENT);
            outbase[((size_t)t << 9) + tid] = hn;
        }
        __syncthreads();

        // ---- fenced 8-block barrier (skip after last step) ----
        if (t < T_LEN - 1) {
            if (tid == 0) {
                __threadfence();   // agent fence: flush block's h stores
                __hip_atomic_fetch_add(mycnt, 1, __ATOMIC_ACQ_REL,
                                       __HIP_MEMORY_SCOPE_AGENT);
                const int tgt = (t + 1) << 3;
                while (__hip_atomic_load(mycnt, __ATOMIC_ACQUIRE,
                                         __HIP_MEMORY_SCOPE_AGENT) < tgt) {
                    __builtin_amdgcn_s_sleep(1);
                }
                __threadfence();   // agent fence: invalidate stale lines
            }
            __syncthreads();
        }
    }
}

// ---------------------------------------------------------------------------
// Output grouped linear, in-place on d_out (holds hs after k_scan).
// One block = 8 rows, 256 threads; w_out column hoisted to registers.
// ---------------------------------------------------------------------------
__global__ __launch_bounds__(256) void k_out(const float* __restrict__ w_out, // [g][i][o]
                                             float* __restrict__ io) {
    __shared__ alignas(16) float ht[8][512];
    const int tid  = threadIdx.x;
    const int row0 = blockIdx.x * 8;

    for (int i = tid; i < 8 * 128; i += 256) {
        int rr = i >> 7, c4 = i & 127;
        ((float4*)ht[rr])[c4] =
            ((const float4*)(io + (size_t)(row0 + rr) * 512))[c4];
    }
    __syncthreads();

    for (int q = 0; q < 2; ++q) {
        const int c = tid + (q << 8);
        const int g = c >> 6, o = c & 63;
        const float* wb = w_out + (g << 12) + o;
        float wcol[64];
#pragma unroll
        for (int ii = 0; ii < 64; ++ii) wcol[ii] = wb[ii << 6];
#pragma unroll 4
        for (int rr = 0; rr < 8; ++rr) {
            float acc = 0.f;
#pragma unroll
            for (int ii = 0; ii < 64; ++ii) acc += ht[rr][(g << 6) + ii] * wcol[ii];
            io[(size_t)(row0 + rr) * 512 + c] = acc;
        }
    }
}

// ---------------------------------------------------------------------------
extern "C" void kernel_launch(void* const* d_in, const int* in_sizes, int n_in,
                              void* d_out, int out_size, void* d_ws, size_t ws_size,
                              hipStream_t stream) {
    const float* x      = (const float*)d_in[0];
    const float* w_in   = (const float*)d_in[1];
    const float* w_rec  = (const float*)d_in[2];
    const float* u_rec  = (const float*)d_in[3];
    const float* gamma  = (const float*)d_in[4];
    const float* beta   = (const float*)d_in[5];
    const float* w_out  = (const float*)d_in[6];
    float* out = (float*)d_out;

    // workspace layout (total 131,207,168 B — under the proven round-2 bound)
    float* w_pre = (float*)d_ws;                          // 32,768,000 f32
    float* hbuf  = w_pre + (size_t)32 * T_LEN * 1024;     // 2*32*512 = 32,768 f32
    int*   cnt   = (int*)(hbuf + 32768);                  // 32 counters * 32 ints

    hipLaunchKernelGGL(k_pre, dim3(2000), dim3(256), 0, stream,
                       x, w_in, w_rec, gamma, beta, w_pre);
    // zero h ping-pong + barrier counters (stream-ordered, graph-capture safe)
    hipMemsetAsync(hbuf, 0, 32768 * sizeof(float) + 1024 * sizeof(int), stream);
    hipLaunchKernelGGL(k_scan, dim3(256), dim3(1024), 0, stream,
                       w_pre, u_rec, out, hbuf, cnt);
    hipLaunchKernelGGL(k_out, dim3(4000), dim3(256), 0, stream, w_out, out);
}

// Round 5
// 8349.337 us; speedup vs baseline: 7.2467x; 1.8417x over previous
//
#include <hip/hip_runtime.h>
#include <cstddef>

#define B_SZ 32
#define T_LEN 1000
#define LN_EPS 1e-5f

// ---------------------------------------------------------------------------
// Fused: h_in = grouped_linear(x, w_in); w = h_in @ Wrec^T; w = LayerNorm(w)
// One block = 16 rows. 256 threads.
// ---------------------------------------------------------------------------
__global__ __launch_bounds__(256) void k_pre(const float* __restrict__ x,
                                             const float* __restrict__ w_in,   // [g][i][o]
                                             const float* __restrict__ w_rec,  // [1024][512]
                                             const float* __restrict__ gamma,
                                             const float* __restrict__ beta,
                                             float* __restrict__ w_pre) {
    __shared__ alignas(16) float xt[16][512];
    __shared__ alignas(16) float hin[16][512];
    __shared__ float redS[16][4];
    __shared__ float redQ[16][4];

    const int tid  = threadIdx.x;
    const int row0 = blockIdx.x * 16;

    // ---- load 16 x-rows into LDS (float4, coalesced) ----
    for (int i = tid; i < 16 * 128; i += 256) {
        int rr = i >> 7, c4 = i & 127;
        ((float4*)xt[rr])[c4] =
            ((const float4*)(x + (size_t)(row0 + rr) * 512))[c4];
    }
    __syncthreads();

    // ---- grouped input projection: hin[rr][c] ----
    for (int q = 0; q < 2; ++q) {
        const int c = tid + (q << 8);
        const int g = c >> 6, o = c & 63;
        const float* wb = w_in + (g << 12) + o;   // stride 64 over i, coalesced over lanes
        float wcol[64];
#pragma unroll
        for (int ii = 0; ii < 64; ++ii) wcol[ii] = wb[ii << 6];
#pragma unroll 4
        for (int rr = 0; rr < 16; ++rr) {
            float acc = 0.f;
#pragma unroll
            for (int ii = 0; ii < 64; ++ii) acc += xt[rr][(g << 6) + ii] * wcol[ii];
            hin[rr][c] = acc;
        }
    }
    __syncthreads();

    // ---- dense GEMM: acc[rr][jj] = hin[rr][:] . w_rec[j0+jj][:] ----
    const int j0 = tid * 4;
    float acc[16][4];
#pragma unroll
    for (int rr = 0; rr < 16; ++rr)
#pragma unroll
        for (int jj = 0; jj < 4; ++jj) acc[rr][jj] = 0.f;

    for (int k = 0; k < 512; k += 4) {
        float4 wv0 = *(const float4*)(w_rec + (size_t)(j0 + 0) * 512 + k);
        float4 wv1 = *(const float4*)(w_rec + (size_t)(j0 + 1) * 512 + k);
        float4 wv2 = *(const float4*)(w_rec + (size_t)(j0 + 2) * 512 + k);
        float4 wv3 = *(const float4*)(w_rec + (size_t)(j0 + 3) * 512 + k);
#pragma unroll
        for (int rr = 0; rr < 16; ++rr) {
            float4 hv = *(const float4*)(&hin[rr][k]);
            acc[rr][0] += hv.x * wv0.x + hv.y * wv0.y + hv.z * wv0.z + hv.w * wv0.w;
            acc[rr][1] += hv.x * wv1.x + hv.y * wv1.y + hv.z * wv1.z + hv.w * wv1.w;
            acc[rr][2] += hv.x * wv2.x + hv.y * wv2.y + hv.z * wv2.z + hv.w * wv2.w;
            acc[rr][3] += hv.x * wv3.x + hv.y * wv3.y + hv.z * wv3.z + hv.w * wv3.w;
        }
    }

    // ---- LayerNorm over j (1024) per row ----
    const int lane = tid & 63, wv = tid >> 6;
#pragma unroll
    for (int rr = 0; rr < 16; ++rr) {
        float s = acc[rr][0] + acc[rr][1] + acc[rr][2] + acc[rr][3];
        float q = acc[rr][0] * acc[rr][0] + acc[rr][1] * acc[rr][1] +
                  acc[rr][2] * acc[rr][2] + acc[rr][3] * acc[rr][3];
#pragma unroll
        for (int off = 1; off < 64; off <<= 1) {
            s += __shfl_xor(s, off);
            q += __shfl_xor(q, off);
        }
        if (lane == 0) { redS[rr][wv] = s; redQ[rr][wv] = q; }
    }
    __syncthreads();

    float4 gv = *(const float4*)(gamma + j0);
    float4 bv = *(const float4*)(beta + j0);
#pragma unroll
    for (int rr = 0; rr < 16; ++rr) {
        float s = redS[rr][0] + redS[rr][1] + redS[rr][2] + redS[rr][3];
        float q = redQ[rr][0] + redQ[rr][1] + redQ[rr][2] + redQ[rr][3];
        float mu  = s * (1.f / 1024.f);
        float var = q * (1.f / 1024.f) - mu * mu;
        float inv = rsqrtf(var + LN_EPS);
        float4 o;
        o.x = (acc[rr][0] - mu) * inv * gv.x + bv.x;
        o.y = (acc[rr][1] - mu) * inv * gv.y + bv.y;
        o.z = (acc[rr][2] - mu) * inv * gv.z + bv.z;
        o.w = (acc[rr][3] - mu) * inv * gv.w + bv.w;
        *(float4*)(w_pre + ((size_t)(row0 + rr) << 10) + j0) = o;
    }
}

// ---------------------------------------------------------------------------
// LiGRU scan, 8 blocks per batch (256 blocks, all co-resident). Pure fp32.
// Cross-block exchange exclusively via agent-scope (sc1) atomics -> coherent
// through memory-side L3; NO cache-flushing threadfence (that was the 14 µs/
// step cost in R4: 32 blocks/XCD x 2 L2-flushes/step serializing at L2).
// w_pre value prefetched at loop top (HBM latency hidden under staging+dot).
// ---------------------------------------------------------------------------
__global__ __launch_bounds__(1024) void k_scan(const float* __restrict__ w_pre,
                                               const float* __restrict__ u,   // [1024][512]
                                               float* __restrict__ hs,        // [B][T][512]
                                               float* hbuf,                   // [2][32][512]
                                               int* cnt) {                    // [32][32]
    __shared__ alignas(16) float hsh[512];
    __shared__ float gsum[128];

    const int tid = threadIdx.x;
    const int b   = blockIdx.x & 31;
    const int s   = blockIdx.x >> 5;
    const int J0  = s << 6;
    const int row = tid >> 3;
    const int kk  = tid & 7;
    const int jj  = (row < 64) ? (J0 + row) : (448 + J0 + row);  // z-rows: 512+J0+(row-64)

    // ---- load this thread's u slice into registers (one-time, f32) ----
    float ur[64];
    {
        const float4* up = (const float4*)(u + (size_t)jj * 512 + (kk << 6));
#pragma unroll
        for (int m = 0; m < 16; ++m) {
            float4 v = up[m];
            ur[4 * m + 0] = v.x; ur[4 * m + 1] = v.y;
            ur[4 * m + 2] = v.z; ur[4 * m + 3] = v.w;
        }
    }

    const float* wbase = w_pre + ((size_t)b * T_LEN) * 1024 + jj;
    float* outbase = hs + ((size_t)b * T_LEN) * 512 + J0;
    int* mycnt = cnt + (b << 5);
    const char* hb8 = (const char*)hsh;

    float hreg = 0.f;   // own h value (tid < 64), carried in f32 across steps

    for (int t = 0; t < T_LEN; ++t) {
        float* hb_in  = hbuf + ((t & 1) << 14) + (b << 9);
        float* hb_out = hbuf + (((t + 1) & 1) << 14) + (b << 9);

        // ---- prefetch this step's w (HBM-cold); consumed after the reduce ----
        float wreg = 0.f;
        if (kk == 0) wreg = wbase[(size_t)t << 10];

        // ---- stage h -> swizzled f32 LDS ----
        // h-chunk c (4 floats) stored at LDS chunk a = (c&~7) | ((c^(c>>4))&7)
        if (tid < 512) {
            float hv = __hip_atomic_load(hb_in + tid, __ATOMIC_RELAXED,
                                         __HIP_MEMORY_SCOPE_AGENT);
            int c = tid >> 2, r = tid & 3;
            int a = (c & ~7) | ((c ^ (c >> 4)) & 7);
            hsh[(a << 2) | r] = hv;
        }
        __syncthreads();

        // ---- dot: 64 f32 MACs via 16 float4 LDS reads (conflict-free) ----
        float acc = 0.f;
        const int base = kk << 8;   // byte base of this thread's 256B h-span
#pragma unroll
        for (int i = 0; i < 16; ++i) {
            int off = base + (((i & 8) | ((i ^ kk) & 7)) << 4);
            float4 hv = *(const float4*)(hb8 + off);
            acc += ur[4 * i + 0] * hv.x + ur[4 * i + 1] * hv.y +
                   ur[4 * i + 2] * hv.z + ur[4 * i + 3] * hv.w;
        }
        acc += __shfl_xor(acc, 1);
        acc += __shfl_xor(acc, 2);
        acc += __shfl_xor(acc, 4);
        if (kk == 0) gsum[row] = acc + wreg;
        __syncthreads();

        // ---- h update (64 threads) ----
        if (tid < 64) {
            float a  = gsum[tid];
            float zl = gsum[64 + tid];
            float z  = 1.f / (1.f + __expf(-zl));
            float hn = z * hreg + (1.f - z) * fmaxf(a, 0.f);
            hreg = hn;
            __hip_atomic_store(hb_out + J0 + tid, hn, __ATOMIC_RELAXED,
                               __HIP_MEMORY_SCOPE_AGENT);
            outbase[((size_t)t << 9) + tid] = hn;
        }
        __syncthreads();

        // ---- 8-block barrier via agent-scope counter (skip after last step) ----
        if (t < T_LEN - 1) {
            if (tid == 0) {
                __hip_atomic_fetch_add(mycnt, 1, __ATOMIC_ACQ_REL,
                                       __HIP_MEMORY_SCOPE_AGENT);
                const int tgt = (t + 1) << 3;
                while (__hip_atomic_load(mycnt, __ATOMIC_ACQUIRE,
                                         __HIP_MEMORY_SCOPE_AGENT) < tgt) {
                    __builtin_amdgcn_s_sleep(1);
                }
            }
            __syncthreads();
        }
    }
}

// ---------------------------------------------------------------------------
// Output grouped linear, in-place on d_out (holds hs after k_scan).
// ---------------------------------------------------------------------------
__global__ __launch_bounds__(256) void k_out(const float* __restrict__ w_out, // [g][i][o]
                                             float* __restrict__ io) {
    __shared__ alignas(16) float ht[8][512];
    const int tid  = threadIdx.x;
    const int row0 = blockIdx.x * 8;

    for (int i = tid; i < 8 * 128; i += 256) {
        int rr = i >> 7, c4 = i & 127;
        ((float4*)ht[rr])[c4] =
            ((const float4*)(io + (size_t)(row0 + rr) * 512))[c4];
    }
    __syncthreads();

    for (int q = 0; q < 2; ++q) {
        const int c = tid + (q << 8);
        const int g = c >> 6, o = c & 63;
        const float* wb = w_out + (g << 12) + o;
        float wcol[64];
#pragma unroll
        for (int ii = 0; ii < 64; ++ii) wcol[ii] = wb[ii << 6];
#pragma unroll 4
        for (int rr = 0; rr < 8; ++rr) {
            float acc = 0.f;
#pragma unroll
            for (int ii = 0; ii < 64; ++ii) acc += ht[rr][(g << 6) + ii] * wcol[ii];
            io[(size_t)(row0 + rr) * 512 + c] = acc;
        }
    }
}

// ---------------------------------------------------------------------------
extern "C" void kernel_launch(void* const* d_in, const int* in_sizes, int n_in,
                              void* d_out, int out_size, void* d_ws, size_t ws_size,
                              hipStream_t stream) {
    const float* x      = (const float*)d_in[0];
    const float* w_in   = (const float*)d_in[1];
    const float* w_rec  = (const float*)d_in[2];
    const float* u_rec  = (const float*)d_in[3];
    const float* gamma  = (const float*)d_in[4];
    const float* beta   = (const float*)d_in[5];
    const float* w_out  = (const float*)d_in[6];
    float* out = (float*)d_out;

    // workspace layout (total 131,207,168 B — under the proven bound)
    float* w_pre = (float*)d_ws;                          // 32,768,000 f32
    float* hbuf  = w_pre + (size_t)32 * T_LEN * 1024;     // 2*32*512 = 32,768 f32
    int*   cnt   = (int*)(hbuf + 32768);                  // 32 counters * 32 ints

    hipLaunchKernelGGL(k_pre, dim3(2000), dim3(256), 0, stream,
                       x, w_in, w_rec, gamma, beta, w_pre);
    // zero h ping-pong + barrier counters (stream-ordered, graph-capture safe)
    hipMemsetAsync(hbuf, 0, 32768 * sizeof(float) + 1024 * sizeof(int), stream);
    hipLaunchKernelGGL(k_scan, dim3(256), dim3(1024), 0, stream,
                       w_pre, u_rec, out, hbuf, cnt);
    hipLaunchKernelGGL(k_out, dim3(4000), dim3(256), 0, stream, w_out, out);
}

// Round 6
// 2458.754 us; speedup vs baseline: 24.6080x; 3.3958x over previous
//
#include <hip/hip_runtime.h>
#include <cstddef>

#define B_SZ 32
#define T_LEN 1000
#define LN_EPS 1e-5f

// ---------------------------------------------------------------------------
// Fused: h_in = grouped_linear(x, w_in); w = h_in @ Wrec^T; w = LayerNorm(w)
// One block = 16 rows. 256 threads.
// ---------------------------------------------------------------------------
__global__ __launch_bounds__(256) void k_pre(const float* __restrict__ x,
                                             const float* __restrict__ w_in,   // [g][i][o]
                                             const float* __restrict__ w_rec,  // [1024][512]
                                             const float* __restrict__ gamma,
                                             const float* __restrict__ beta,
                                             float* __restrict__ w_pre) {
    __shared__ alignas(16) float xt[16][512];
    __shared__ alignas(16) float hin[16][512];
    __shared__ float redS[16][4];
    __shared__ float redQ[16][4];

    const int tid  = threadIdx.x;
    const int row0 = blockIdx.x * 16;

    // ---- load 16 x-rows into LDS (float4, coalesced) ----
    for (int i = tid; i < 16 * 128; i += 256) {
        int rr = i >> 7, c4 = i & 127;
        ((float4*)xt[rr])[c4] =
            ((const float4*)(x + (size_t)(row0 + rr) * 512))[c4];
    }
    __syncthreads();

    // ---- grouped input projection: hin[rr][c] ----
    for (int q = 0; q < 2; ++q) {
        const int c = tid + (q << 8);
        const int g = c >> 6, o = c & 63;
        const float* wb = w_in + (g << 12) + o;   // stride 64 over i, coalesced over lanes
        float wcol[64];
#pragma unroll
        for (int ii = 0; ii < 64; ++ii) wcol[ii] = wb[ii << 6];
#pragma unroll 4
        for (int rr = 0; rr < 16; ++rr) {
            float acc = 0.f;
#pragma unroll
            for (int ii = 0; ii < 64; ++ii) acc += xt[rr][(g << 6) + ii] * wcol[ii];
            hin[rr][c] = acc;
        }
    }
    __syncthreads();

    // ---- dense GEMM: acc[rr][jj] = hin[rr][:] . w_rec[j0+jj][:] ----
    const int j0 = tid * 4;
    float acc[16][4];
#pragma unroll
    for (int rr = 0; rr < 16; ++rr)
#pragma unroll
        for (int jj = 0; jj < 4; ++jj) acc[rr][jj] = 0.f;

    for (int k = 0; k < 512; k += 4) {
        float4 wv0 = *(const float4*)(w_rec + (size_t)(j0 + 0) * 512 + k);
        float4 wv1 = *(const float4*)(w_rec + (size_t)(j0 + 1) * 512 + k);
        float4 wv2 = *(const float4*)(w_rec + (size_t)(j0 + 2) * 512 + k);
        float4 wv3 = *(const float4*)(w_rec + (size_t)(j0 + 3) * 512 + k);
#pragma unroll
        for (int rr = 0; rr < 16; ++rr) {
            float4 hv = *(const float4*)(&hin[rr][k]);
            acc[rr][0] += hv.x * wv0.x + hv.y * wv0.y + hv.z * wv0.z + hv.w * wv0.w;
            acc[rr][1] += hv.x * wv1.x + hv.y * wv1.y + hv.z * wv1.z + hv.w * wv1.w;
            acc[rr][2] += hv.x * wv2.x + hv.y * wv2.y + hv.z * wv2.z + hv.w * wv2.w;
            acc[rr][3] += hv.x * wv3.x + hv.y * wv3.y + hv.z * wv3.z + hv.w * wv3.w;
        }
    }

    // ---- LayerNorm over j (1024) per row ----
    const int lane = tid & 63, wv = tid >> 6;
#pragma unroll
    for (int rr = 0; rr < 16; ++rr) {
        float s = acc[rr][0] + acc[rr][1] + acc[rr][2] + acc[rr][3];
        float q = acc[rr][0] * acc[rr][0] + acc[rr][1] * acc[rr][1] +
                  acc[rr][2] * acc[rr][2] + acc[rr][3] * acc[rr][3];
#pragma unroll
        for (int off = 1; off < 64; off <<= 1) {
            s += __shfl_xor(s, off);
            q += __shfl_xor(q, off);
        }
        if (lane == 0) { redS[rr][wv] = s; redQ[rr][wv] = q; }
    }
    __syncthreads();

    float4 gv = *(const float4*)(gamma + j0);
    float4 bv = *(const float4*)(beta + j0);
#pragma unroll
    for (int rr = 0; rr < 16; ++rr) {
        float s = redS[rr][0] + redS[rr][1] + redS[rr][2] + redS[rr][3];
        float q = redQ[rr][0] + redQ[rr][1] + redQ[rr][2] + redQ[rr][3];
        float mu  = s * (1.f / 1024.f);
        float var = q * (1.f / 1024.f) - mu * mu;
        float inv = rsqrtf(var + LN_EPS);
        float4 o;
        o.x = (acc[rr][0] - mu) * inv * gv.x + bv.x;
        o.y = (acc[rr][1] - mu) * inv * gv.y + bv.y;
        o.z = (acc[rr][2] - mu) * inv * gv.z + bv.z;
        o.w = (acc[rr][3] - mu) * inv * gv.w + bv.w;
        *(float4*)(w_pre + ((size_t)(row0 + rr) << 10) + j0) = o;
    }
}

// ---------------------------------------------------------------------------
// LiGRU scan, 8 blocks per batch (256 blocks, all co-resident). Pure fp32.
// Sync is DATA-FLOW ONLY: each h word carries a 2-bit step stamp in its low
// mantissa bits (error 2^-21, invisible). Producer: one relaxed agent store
// of (h | stamp). Consumer: poll own word until stamp == t&3. Parity ping-
// pong (slot t&1) + dataflow bounds skew to 1 step -> no overwrite hazard,
// no counter barrier, no fences, no RMW atomics. 2 syncthreads/step.
// ---------------------------------------------------------------------------
__global__ __launch_bounds__(1024) void k_scan(const float* __restrict__ w_pre,
                                               const float* __restrict__ u,   // [1024][512]
                                               float* __restrict__ hs,        // [B][T][512]
                                               unsigned int* hbuf) {          // [2][32][512]
    __shared__ alignas(16) float hsh[512];
    __shared__ float gsum[128];

    const int tid = threadIdx.x;
    const int b   = blockIdx.x & 31;
    const int s   = blockIdx.x >> 5;
    const int J0  = s << 6;
    const int row = tid >> 3;
    const int kk  = tid & 7;
    const int jj  = (row < 64) ? (J0 + row) : (448 + J0 + row);  // z-rows: 512+J0+(row-64)

    // ---- load this thread's u slice into registers (one-time, f32) ----
    float ur[64];
    {
        const float4* up = (const float4*)(u + (size_t)jj * 512 + (kk << 6));
#pragma unroll
        for (int m = 0; m < 16; ++m) {
            float4 v = up[m];
            ur[4 * m + 0] = v.x; ur[4 * m + 1] = v.y;
            ur[4 * m + 2] = v.z; ur[4 * m + 3] = v.w;
        }
    }

    const float* wbase = w_pre + ((size_t)b * T_LEN) * 1024 + jj;
    float* outbase = hs + ((size_t)b * T_LEN) * 512 + J0;
    const char* hb8 = (const char*)hsh;

    float hreg = 0.f;   // own h value (tid < 64), carried in f32 across steps

    for (int t = 0; t < T_LEN; ++t) {
        unsigned int* in_w  = hbuf + ((((t & 1) << 5) | b) << 9);
        unsigned int* out_w = hbuf + (((((t + 1) & 1) << 5) | b) << 9);

        // ---- prefetch this step's w (HBM-cold); consumed after the reduce ----
        float wreg = 0.f;
        if (kk == 0) wreg = wbase[(size_t)t << 10];

        // ---- poll + stage h -> swizzled f32 LDS ----
        // h-chunk c (4 floats) stored at LDS chunk a = (c&~7) | ((c^(c>>4))&7)
        if (tid < 512) {
            const unsigned int want = (unsigned)t & 3u;
            unsigned int v = __hip_atomic_load(in_w + tid, __ATOMIC_RELAXED,
                                               __HIP_MEMORY_SCOPE_AGENT);
            while ((v & 3u) != want) {
                v = __hip_atomic_load(in_w + tid, __ATOMIC_RELAXED,
                                      __HIP_MEMORY_SCOPE_AGENT);
            }
            float hv = __builtin_bit_cast(float, v);
            int c = tid >> 2, r = tid & 3;
            int a = (c & ~7) | ((c ^ (c >> 4)) & 7);
            hsh[(a << 2) | r] = hv;
        }
        __syncthreads();

        // ---- dot: 64 f32 MACs via 16 float4 LDS reads, 4 acc chains ----
        float a0 = 0.f, a1 = 0.f, a2 = 0.f, a3 = 0.f;
        const int base = kk << 8;   // byte base of this thread's 256B h-span
#pragma unroll
        for (int i = 0; i < 16; ++i) {
            int off = base + (((i & 8) | ((i ^ kk) & 7)) << 4);
            float4 hv = *(const float4*)(hb8 + off);
            a0 += ur[4 * i + 0] * hv.x;
            a1 += ur[4 * i + 1] * hv.y;
            a2 += ur[4 * i + 2] * hv.z;
            a3 += ur[4 * i + 3] * hv.w;
        }
        float acc = (a0 + a1) + (a2 + a3);
        acc += __shfl_xor(acc, 1);
        acc += __shfl_xor(acc, 2);
        acc += __shfl_xor(acc, 4);
        if (kk == 0) gsum[row] = acc + wreg;
        __syncthreads();

        // ---- h update (64 threads): store stamped word, no fence needed ----
        if (tid < 64) {
            float a  = gsum[tid];
            float zl = gsum[64 + tid];
            float z  = 1.f / (1.f + __expf(-zl));
            float hn = z * hreg + (1.f - z) * fmaxf(a, 0.f);
            hreg = hn;
            unsigned int bits = (__builtin_bit_cast(unsigned int, hn) & ~3u) |
                                ((unsigned)(t + 1) & 3u);
            __hip_atomic_store(out_w + J0 + tid, bits, __ATOMIC_RELAXED,
                               __HIP_MEMORY_SCOPE_AGENT);
            outbase[((size_t)t << 9) + tid] = hn;
        }
        // no third syncthreads: all hsh/gsum reads for step t complete before
        // sync#2; staging for t+1 only touches hsh after it.
    }
}

// ---------------------------------------------------------------------------
// Output grouped linear, in-place on d_out (holds hs after k_scan).
// ---------------------------------------------------------------------------
__global__ __launch_bounds__(256) void k_out(const float* __restrict__ w_out, // [g][i][o]
                                             float* __restrict__ io) {
    __shared__ alignas(16) float ht[8][512];
    const int tid  = threadIdx.x;
    const int row0 = blockIdx.x * 8;

    for (int i = tid; i < 8 * 128; i += 256) {
        int rr = i >> 7, c4 = i & 127;
        ((float4*)ht[rr])[c4] =
            ((const float4*)(io + (size_t)(row0 + rr) * 512))[c4];
    }
    __syncthreads();

    for (int q = 0; q < 2; ++q) {
        const int c = tid + (q << 8);
        const int g = c >> 6, o = c & 63;
        const float* wb = w_out + (g << 12) + o;
        float wcol[64];
#pragma unroll
        for (int ii = 0; ii < 64; ++ii) wcol[ii] = wb[ii << 6];
#pragma unroll 4
        for (int rr = 0; rr < 8; ++rr) {
            float acc = 0.f;
#pragma unroll
            for (int ii = 0; ii < 64; ++ii) acc += ht[rr][(g << 6) + ii] * wcol[ii];
            io[(size_t)(row0 + rr) * 512 + c] = acc;
        }
    }
}

// ---------------------------------------------------------------------------
extern "C" void kernel_launch(void* const* d_in, const int* in_sizes, int n_in,
                              void* d_out, int out_size, void* d_ws, size_t ws_size,
                              hipStream_t stream) {
    const float* x      = (const float*)d_in[0];
    const float* w_in   = (const float*)d_in[1];
    const float* w_rec  = (const float*)d_in[2];
    const float* u_rec  = (const float*)d_in[3];
    const float* gamma  = (const float*)d_in[4];
    const float* beta   = (const float*)d_in[5];
    const float* w_out  = (const float*)d_in[6];
    float* out = (float*)d_out;

    // workspace layout (131,203,072 B total — under the proven bound)
    float*        w_pre = (float*)d_ws;                       // 32,768,000 f32
    unsigned int* hbuf  = (unsigned int*)(w_pre + (size_t)32 * T_LEN * 1024); // [2][32][512] u32

    hipLaunchKernelGGL(k_pre, dim3(2000), dim3(256), 0, stream,
                       x, w_in, w_rec, gamma, beta, w_pre);
    // zero stamped h buffer: stamp 0 == initial h = 0 (stream-ordered, capture-safe)
    hipMemsetAsync(hbuf, 0, 2 * 32 * 512 * sizeof(unsigned int), stream);
    hipLaunchKernelGGL(k_scan, dim3(256), dim3(1024), 0, stream,
                       w_pre, u_rec, out, hbuf);
    hipLaunchKernelGGL(k_out, dim3(4000), dim3(256), 0, stream, w_out, out);
}

// Round 7
// 1844.209 us; speedup vs baseline: 32.8081x; 1.3332x over previous
//
#include <hip/hip_runtime.h>
#include <cstddef>

#define B_SZ 32
#define T_LEN 1000
#define LN_EPS 1e-5f

typedef short bf16x8 __attribute__((ext_vector_type(8)));
typedef float f32x4 __attribute__((ext_vector_type(4)));

__device__ __forceinline__ unsigned short f2bf(float f) {
    unsigned u = __builtin_bit_cast(unsigned, f);
    u += 0x7FFFu + ((u >> 16) & 1u);          // RNE
    return (unsigned short)(u >> 16);
}

// ---------------------------------------------------------------------------
// kw: pack w_rec [1024][512] f32 into bf16 B-fragments for mfma 16x16x32:
// wrt[kt][nt][lane][j] = bf16(w_rec[nt*16 + (lane&15)][kt*32 + (lane>>4)*8 + j])
// 16 kt x 64 nt x 64 lanes; each thread writes one 16B fragment slice.
// ---------------------------------------------------------------------------
__global__ __launch_bounds__(256) void kw(const float* __restrict__ w_rec,
                                          unsigned short* __restrict__ wrt) {
    int idx  = blockIdx.x * 256 + threadIdx.x;   // 65536 total
    int lane = idx & 63;
    int nt   = (idx >> 6) & 63;
    int kt   = idx >> 12;
    int n    = nt * 16 + (lane & 15);
    int k0   = kt * 32 + (lane >> 4) * 8;
    const float* src = w_rec + (size_t)n * 512 + k0;
    unsigned short* dst = wrt + (size_t)idx * 8;
#pragma unroll
    for (int j = 0; j < 8; ++j) dst[j] = f2bf(src[j]);
}

// ---------------------------------------------------------------------------
// k1: grouped input projection x @ w_in -> h_in (bf16). 16 rows/block.
// ---------------------------------------------------------------------------
__global__ __launch_bounds__(256) void k1(const float* __restrict__ x,
                                          const float* __restrict__ w_in,   // [g][i][o]
                                          unsigned short* __restrict__ hin) {
    __shared__ alignas(16) float xt[16][512];
    const int tid  = threadIdx.x;
    const int row0 = blockIdx.x * 16;

    for (int i = tid; i < 16 * 128; i += 256) {
        int rr = i >> 7, c4 = i & 127;
        ((float4*)xt[rr])[c4] =
            ((const float4*)(x + (size_t)(row0 + rr) * 512))[c4];
    }
    __syncthreads();

    for (int q = 0; q < 2; ++q) {
        const int c = tid + (q << 8);
        const int g = c >> 6, o = c & 63;
        const float* wb = w_in + (g << 12) + o;
        float wcol[64];
#pragma unroll
        for (int ii = 0; ii < 64; ++ii) wcol[ii] = wb[ii << 6];
#pragma unroll 4
        for (int rr = 0; rr < 16; ++rr) {
            float acc = 0.f;
#pragma unroll
            for (int ii = 0; ii < 64; ++ii) acc += xt[rr][(g << 6) + ii] * wcol[ii];
            hin[(size_t)(row0 + rr) * 512 + c] = f2bf(acc);
        }
    }
}

// ---------------------------------------------------------------------------
// k2: w_pre = LayerNorm(h_in @ w_rec^T) via MFMA 16x16x32 bf16.
// Block = 32 rows x 1024 cols, K=512. 256 threads (4 waves); wave w owns
// frag-cols [w*16, w*16+16) (cols w*256..+256), both 16-row frag-rows.
// A staged in LDS (pad to 536 bf16/row: bank-stride 12 -> 2-way, free).
// B-frags read straight from L2 (packed by kw, 16B/lane coalesced).
// LN stats in f32 from f32 accumulators; fused epilogue.
// ---------------------------------------------------------------------------
#define ALD 536   // 512 + 24 pad, keeps 16B alignment, conflict-free frag reads
__global__ __launch_bounds__(256) void k2(const unsigned short* __restrict__ hin,
                                          const unsigned short* __restrict__ wrt,
                                          const float* __restrict__ gamma,
                                          const float* __restrict__ beta,
                                          float* __restrict__ w_pre) {
    __shared__ alignas(16) unsigned short At[32 * ALD];
    __shared__ float redS[4][32];
    __shared__ float redQ[4][32];
    __shared__ float stat[2][32];

    const int tid  = threadIdx.x;
    const int w    = tid >> 6;
    const int l    = tid & 63;
    const int kgrp = l >> 4;
    const int lc   = l & 15;
    const int row0 = blockIdx.x * 32;

    // ---- stage A tile: 32 rows x 512 bf16 -> padded LDS ----
    for (int sidx = tid; sidx < 2048; sidx += 256) {
        int r = sidx >> 6, sg = sidx & 63;
        *(bf16x8*)(At + r * ALD + sg * 8) =
            *(const bf16x8*)(hin + (size_t)(row0 + r) * 512 + sg * 8);
    }
    __syncthreads();

    // ---- MFMA main loop ----
    f32x4 acc[2][16];
#pragma unroll
    for (int fr = 0; fr < 2; ++fr)
#pragma unroll
        for (int n = 0; n < 16; ++n) acc[fr][n] = f32x4{0.f, 0.f, 0.f, 0.f};

    for (int kt = 0; kt < 16; ++kt) {
        bf16x8 a0 = *(const bf16x8*)(At + (lc)      * ALD + kt * 32 + kgrp * 8);
        bf16x8 a1 = *(const bf16x8*)(At + (16 + lc) * ALD + kt * 32 + kgrp * 8);
        const unsigned short* bb =
            wrt + (((size_t)kt * 64 + w * 16) * 64 + l) * 8;
#pragma unroll
        for (int ntl = 0; ntl < 16; ++ntl) {
            bf16x8 bf = *(const bf16x8*)(bb + (size_t)ntl * 512);
            acc[0][ntl] = __builtin_amdgcn_mfma_f32_16x16x32_bf16(a0, bf, acc[0][ntl], 0, 0, 0);
            acc[1][ntl] = __builtin_amdgcn_mfma_f32_16x16x32_bf16(a1, bf, acc[1][ntl], 0, 0, 0);
        }
    }

    // ---- LN stats: per-lane partials for its 8 rows (2 fr x 4 reg) ----
    float sums[2][4] = {{0.f}}, sqs[2][4] = {{0.f}};
#pragma unroll
    for (int fr = 0; fr < 2; ++fr)
#pragma unroll
        for (int ntl = 0; ntl < 16; ++ntl)
#pragma unroll
            for (int r = 0; r < 4; ++r) {
                float v = acc[fr][ntl][r];
                sums[fr][r] += v;
                sqs[fr][r]  += v * v;
            }
#pragma unroll
    for (int off = 1; off < 16; off <<= 1)
#pragma unroll
        for (int fr = 0; fr < 2; ++fr)
#pragma unroll
            for (int r = 0; r < 4; ++r) {
                sums[fr][r] += __shfl_xor(sums[fr][r], off);
                sqs[fr][r]  += __shfl_xor(sqs[fr][r], off);
            }
    if (lc == 0) {
#pragma unroll
        for (int fr = 0; fr < 2; ++fr)
#pragma unroll
            for (int r = 0; r < 4; ++r) {
                redS[w][fr * 16 + kgrp * 4 + r] = sums[fr][r];
                redQ[w][fr * 16 + kgrp * 4 + r] = sqs[fr][r];
            }
    }
    __syncthreads();
    if (tid < 32) {
        float S = redS[0][tid] + redS[1][tid] + redS[2][tid] + redS[3][tid];
        float Q = redQ[0][tid] + redQ[1][tid] + redQ[2][tid] + redQ[3][tid];
        float mu  = S * (1.f / 1024.f);
        float var = Q * (1.f / 1024.f) - mu * mu;
        stat[0][tid] = mu;
        stat[1][tid] = rsqrtf(var + LN_EPS);
    }
    __syncthreads();

    // ---- fused LN epilogue + store ----
#pragma unroll
    for (int ntl = 0; ntl < 16; ++ntl) {
        const int col = (w << 8) + (ntl << 4) + lc;
        const float g = gamma[col], bt = beta[col];
#pragma unroll
        for (int fr = 0; fr < 2; ++fr)
#pragma unroll
            for (int r = 0; r < 4; ++r) {
                const int row = fr * 16 + kgrp * 4 + r;
                const float mu  = stat[0][row];
                const float inv = stat[1][row];
                w_pre[((size_t)(row0 + row) << 10) + col] =
                    (acc[fr][ntl][r] - mu) * inv * g + bt;
            }
    }
}

// ---------------------------------------------------------------------------
// LiGRU scan (byte-identical to R6): 8 blocks/batch, dataflow-stamp sync.
// ---------------------------------------------------------------------------
__global__ __launch_bounds__(1024) void k_scan(const float* __restrict__ w_pre,
                                               const float* __restrict__ u,   // [1024][512]
                                               float* __restrict__ hs,        // [B][T][512]
                                               unsigned int* hbuf) {          // [2][32][512]
    __shared__ alignas(16) float hsh[512];
    __shared__ float gsum[128];

    const int tid = threadIdx.x;
    const int b   = blockIdx.x & 31;
    const int s   = blockIdx.x >> 5;
    const int J0  = s << 6;
    const int row = tid >> 3;
    const int kk  = tid & 7;
    const int jj  = (row < 64) ? (J0 + row) : (448 + J0 + row);

    float ur[64];
    {
        const float4* up = (const float4*)(u + (size_t)jj * 512 + (kk << 6));
#pragma unroll
        for (int m = 0; m < 16; ++m) {
            float4 v = up[m];
            ur[4 * m + 0] = v.x; ur[4 * m + 1] = v.y;
            ur[4 * m + 2] = v.z; ur[4 * m + 3] = v.w;
        }
    }

    const float* wbase = w_pre + ((size_t)b * T_LEN) * 1024 + jj;
    float* outbase = hs + ((size_t)b * T_LEN) * 512 + J0;
    const char* hb8 = (const char*)hsh;

    float hreg = 0.f;

    for (int t = 0; t < T_LEN; ++t) {
        unsigned int* in_w  = hbuf + ((((t & 1) << 5) | b) << 9);
        unsigned int* out_w = hbuf + (((((t + 1) & 1) << 5) | b) << 9);

        float wreg = 0.f;
        if (kk == 0) wreg = wbase[(size_t)t << 10];

        if (tid < 512) {
            const unsigned int want = (unsigned)t & 3u;
            unsigned int v = __hip_atomic_load(in_w + tid, __ATOMIC_RELAXED,
                                               __HIP_MEMORY_SCOPE_AGENT);
            while ((v & 3u) != want) {
                v = __hip_atomic_load(in_w + tid, __ATOMIC_RELAXED,
                                      __HIP_MEMORY_SCOPE_AGENT);
            }
            float hv = __builtin_bit_cast(float, v);
            int c = tid >> 2, r = tid & 3;
            int a = (c & ~7) | ((c ^ (c >> 4)) & 7);
            hsh[(a << 2) | r] = hv;
        }
        __syncthreads();

        float a0 = 0.f, a1 = 0.f, a2 = 0.f, a3 = 0.f;
        const int base = kk << 8;
#pragma unroll
        for (int i = 0; i < 16; ++i) {
            int off = base + (((i & 8) | ((i ^ kk) & 7)) << 4);
            float4 hv = *(const float4*)(hb8 + off);
            a0 += ur[4 * i + 0] * hv.x;
            a1 += ur[4 * i + 1] * hv.y;
            a2 += ur[4 * i + 2] * hv.z;
            a3 += ur[4 * i + 3] * hv.w;
        }
        float acc = (a0 + a1) + (a2 + a3);
        acc += __shfl_xor(acc, 1);
        acc += __shfl_xor(acc, 2);
        acc += __shfl_xor(acc, 4);
        if (kk == 0) gsum[row] = acc + wreg;
        __syncthreads();

        if (tid < 64) {
            float a  = gsum[tid];
            float zl = gsum[64 + tid];
            float z  = 1.f / (1.f + __expf(-zl));
            float hn = z * hreg + (1.f - z) * fmaxf(a, 0.f);
            hreg = hn;
            unsigned int bits = (__builtin_bit_cast(unsigned int, hn) & ~3u) |
                                ((unsigned)(t + 1) & 3u);
            __hip_atomic_store(out_w + J0 + tid, bits, __ATOMIC_RELAXED,
                               __HIP_MEMORY_SCOPE_AGENT);
            outbase[((size_t)t << 9) + tid] = hn;
        }
    }
}

// ---------------------------------------------------------------------------
// Output grouped linear, in-place on d_out (holds hs after k_scan).
// ---------------------------------------------------------------------------
__global__ __launch_bounds__(256) void k_out(const float* __restrict__ w_out, // [g][i][o]
                                             float* __restrict__ io) {
    __shared__ alignas(16) float ht[8][512];
    const int tid  = threadIdx.x;
    const int row0 = blockIdx.x * 8;

    for (int i = tid; i < 8 * 128; i += 256) {
        int rr = i >> 7, c4 = i & 127;
        ((float4*)ht[rr])[c4] =
            ((const float4*)(io + (size_t)(row0 + rr) * 512))[c4];
    }
    __syncthreads();

    for (int q = 0; q < 2; ++q) {
        const int c = tid + (q << 8);
        const int g = c >> 6, o = c & 63;
        const float* wb = w_out + (g << 12) + o;
        float wcol[64];
#pragma unroll
        for (int ii = 0; ii < 64; ++ii) wcol[ii] = wb[ii << 6];
#pragma unroll 4
        for (int rr = 0; rr < 8; ++rr) {
            float acc = 0.f;
#pragma unroll
            for (int ii = 0; ii < 64; ++ii) acc += ht[rr][(g << 6) + ii] * wcol[ii];
            io[(size_t)(row0 + rr) * 512 + c] = acc;
        }
    }
}

// ---------------------------------------------------------------------------
extern "C" void kernel_launch(void* const* d_in, const int* in_sizes, int n_in,
                              void* d_out, int out_size, void* d_ws, size_t ws_size,
                              hipStream_t stream) {
    const float* x      = (const float*)d_in[0];
    const float* w_in   = (const float*)d_in[1];
    const float* w_rec  = (const float*)d_in[2];
    const float* u_rec  = (const float*)d_in[3];
    const float* gamma  = (const float*)d_in[4];
    const float* beta   = (const float*)d_in[5];
    const float* w_out  = (const float*)d_in[6];
    float* out = (float*)d_out;

    // workspace layout (131,203,072 B — same proven bound as R6)
    float*        w_pre = (float*)d_ws;                       // 32,768,000 f32
    unsigned int* hbuf  = (unsigned int*)(w_pre + (size_t)32 * T_LEN * 1024); // [2][32][512]

    // d_out staging (dead until k_scan overwrites it):
    //   [0 .. 32.768 MB): h_in bf16 [32000][512]
    //   [32.768 .. 33.817 MB): packed w_rec bf16 fragments (1 MB)
    unsigned short* hin = (unsigned short*)d_out;
    unsigned short* wrt = hin + (size_t)32000 * 512;

    hipLaunchKernelGGL(kw, dim3(256), dim3(256), 0, stream, w_rec, wrt);
    hipLaunchKernelGGL(k1, dim3(2000), dim3(256), 0, stream, x, w_in, hin);
    hipLaunchKernelGGL(k2, dim3(1000), dim3(256), 0, stream,
                       hin, wrt, gamma, beta, w_pre);
    hipMemsetAsync(hbuf, 0, 2 * 32 * 512 * sizeof(unsigned int), stream);
    hipLaunchKernelGGL(k_scan, dim3(256), dim3(1024), 0, stream,
                       w_pre, u_rec, out, hbuf);
    hipLaunchKernelGGL(k_out, dim3(4000), dim3(256), 0, stream, w_out, out);
}